// Round 2
// baseline (217.545 us; speedup 1.0000x reference)
//
#include <hip/hip_runtime.h>
#include <hip/hip_cooperative_groups.h>
#include <stdint.h>

namespace cg = cooperative_groups;

#define N 8192
#define NCLS 80
#define NW 128              // N/64 keep-mask words
#define PAIR_CAP (1 << 21)  // 2M pairs (8 MB) -- expected E ~ 2-5K
#define ELDS_CAP 8192       // edges staged in LDS for the fixpoint
#define NBLK 256
#define NTHR 256
#define NOWN 32             // elements owned per block (256*32 = 8192)
#define NJOBS 528           // 32*33/2 upper-triangle 256x256 tile jobs

// Key: ascending key == descending conf for valid (conf>0.5 => positive
// float => bit-monotonic); invalid sort last, tie-broken by index (stable).
__device__ __forceinline__ unsigned long long makeKey(float c, int idx) {
    unsigned int kb = (c > 0.5f) ? ~__float_as_uint(c) : 0xFFFFFFFFu;
    return ((unsigned long long)kb << 32) | (unsigned int)idx;
}

// One cooperative kernel, 2 grid.syncs total:
//   phase A: per-block-local rank (keys re-derived from conf), argmax,
//            scatter into sorted order, block-local V  -- no atomics
//   sync#1
//   phase B: sparse suppression-pair extraction (atomic emit)
//   sync#2
//   phase C: per-block redundant Jacobi fixpoint (edges in LDS) + output
__global__ __launch_bounds__(NTHR) void k_fused(
    const float* __restrict__ box,
    const float* __restrict__ conf,
    const float* __restrict__ logits,
    float4* __restrict__ sbx,
    float* __restrict__ sarea,
    int* __restrict__ scls,
    unsigned int* __restrict__ pairs,
    int* __restrict__ paircnt,
    float* __restrict__ out)
{
#pragma clang fp contract(off)
    cg::grid_group grid = cg::this_grid();
    const int tid = threadIdx.x;
    const int bid = blockIdx.x;

    __shared__ unsigned long long tile[1024];   // 8 KB key-chunk staging
    __shared__ int vpart[4];
    __shared__ float4 colb[256];                // phase B staged columns
    __shared__ float  cola[256];
    __shared__ int    colc[256];
    __shared__ unsigned long long keep[NW];     // phase C fixpoint state
    __shared__ unsigned long long sn[NW];
    __shared__ unsigned int eLds[ELDS_CAP];     // 32 KB edge staging
    __shared__ int chg;

    // ================= phase A: rank + argmax + scatter (no syncs) ======
    if (bid == 0 && tid == 0) *paircnt = 0;     // visible after sync#1

    const int i0 = bid * NOWN;
    const int e = tid >> 3;                     // owned element 0..31
    const int s = tid & 7;                      // 8-way slice within element
    const float myConf = conf[i0 + e];
    const unsigned long long myKey = makeKey(myConf, i0 + e);

    int rr = 0;       // partial rank (this slice's count of keys < myKey)
    int vloc = 0;     // valid-count over this thread's staged confs
    for (int ch = 0; ch < 8; ++ch) {
        float4 c4 = ((const float4*)conf)[ch * 256 + tid];
        int base = ch * 1024 + tid * 4;
        tile[tid * 4 + 0] = makeKey(c4.x, base + 0);
        tile[tid * 4 + 1] = makeKey(c4.y, base + 1);
        tile[tid * 4 + 2] = makeKey(c4.z, base + 2);
        tile[tid * 4 + 3] = makeKey(c4.w, base + 3);
        vloc += (c4.x > 0.5f) + (c4.y > 0.5f) + (c4.z > 0.5f) + (c4.w > 0.5f);
        __syncthreads();
        // interleaved slice j = jj*8 + s: 8 distinct u64 addresses per
        // wave-row land on 16 distinct banks (broadcast x8) -> conflict-free
#pragma unroll 32
        for (int jj = 0; jj < 128; ++jj)
            rr += (tile[(jj << 3) | s] < myKey) ? 1 : 0;
        __syncthreads();
    }
    // rank reduce across the 8-thread group (result lands at s==0)
    rr += __shfl_down(rr, 4, 8);
    rr += __shfl_down(rr, 2, 8);
    rr += __shfl_down(rr, 1, 8);

    // V reduce across the block (each conf counted exactly once)
    int vs = vloc;
    for (int off = 32; off; off >>= 1) vs += __shfl_down(vs, off);
    if ((tid & 63) == 0) vpart[tid >> 6] = vs;

    // argmax over 80 logits, 10 per slice-thread (first-max-wins exact:
    // strict > locally; combine prefers greater value, tie -> lower index)
    const float2* lp2 = (const float2*)(logits + (size_t)(i0 + e) * NCLS + s * 10);
    float best = -INFINITY;
    int bi = s * 10;
#pragma unroll 5
    for (int j = 0; j < 5; ++j) {
        float2 v = lp2[j];
        if (v.x > best) { best = v.x; bi = s * 10 + 2 * j; }
        if (v.y > best) { best = v.y; bi = s * 10 + 2 * j + 1; }
    }
    for (int off = 4; off; off >>= 1) {
        float ob = __shfl_down(best, off, 8);
        int oi = __shfl_down(bi, off, 8);
        if (ob > best || (ob == best && oi < bi)) { best = ob; bi = oi; }
    }
    __syncthreads();
    const int V = vpart[0] + vpart[1] + vpart[2] + vpart[3];

    if (s == 0) {   // group leader scatters its element into sorted order
        float4 b = ((const float4*)box)[i0 + e];    // x, y, w, h
        float hw = b.z * 0.5f, hh = b.w * 0.5f;     // == w/2 exactly
        sbx[rr]   = make_float4(b.x - hw, b.y - hh, b.x + hw, b.y + hh);
        sarea[rr] = b.z * b.w;
        scls[rr]  = bi;
    }
    grid.sync();    // ======== sync#1: sorted arrays + paircnt=0 visible ==

    // ================= phase B: suppression-pair extraction =============
    for (int t = bid; t < NJOBS; t += NBLK) {
        // decode upper-triangle job t -> (rbk, cbk), rbk <= cbk < 32
        int rem = t, rbk = 0;
        while (rem >= 32 - rbk) { rem -= 32 - rbk; ++rbk; }
        int cbk = rbk + rem;
        int rbase = rbk << 8, cbase = cbk << 8;
        if (rbase < V && cbase < V) {
            colb[tid] = sbx[cbase + tid];
            cola[tid] = sarea[cbase + tid];
            colc[tid] = scls[cbase + tid];
            __syncthreads();
            int r = rbase + tid;
            if (r < V) {
                float4 rb4 = sbx[r];
                float rar = sarea[r];
                int rcls = scls[r];
#pragma unroll 4
                for (int k = 0; k < 256; ++k) {
                    int c = cbase + k;
                    float4 c4 = colb[k];
                    // exact float32 op order of the reference:
                    float iw = fminf(rb4.z, c4.z) - fmaxf(rb4.x, c4.x);
                    iw = fmaxf(iw, 0.0f);
                    float ih = fminf(rb4.w, c4.w) - fmaxf(rb4.y, c4.y);
                    ih = fmaxf(ih, 0.0f);
                    float inter = iw * ih;
                    float uni = rar + cola[k] - inter;
                    float iou = __fdiv_rn(inter, uni);  // IEEE-rounded divide
                    bool sup = (iou > 0.5f) & (colc[k] == rcls) & (c > r) & (c < V);
                    if (sup) {
                        int idx = atomicAdd(paircnt, 1);
                        if (idx < PAIR_CAP)
                            pairs[idx] = ((unsigned int)r << 13) | (unsigned int)c;
                    }
                }
            }
            __syncthreads();   // protect col* before next job's staging
        }
    }
    grid.sync();    // ======== sync#2: pairs + paircnt visible ============

    // ========= phase C: per-block redundant fixpoint + owned output =====
    // keep_{t+1}[c] = valid[c] & !exists edge r->c with keep_t[r].
    // Edges strictly increase rank (DAG) => unique fixpoint == greedy scan.
    int E = *paircnt; if (E > PAIR_CAP) E = PAIR_CAP;
    const bool inLds = (E <= ELDS_CAP);
    if (inLds)
        for (int eI = tid; eI < E; eI += NTHR) eLds[eI] = pairs[eI];

    const int fullw = V >> 6, remb = V & 63;
    unsigned long long vm = 0ULL;
    if (tid < NW) {
        vm = (tid < fullw) ? ~0ULL
           : (tid == fullw && remb) ? ((1ULL << remb) - 1ULL) : 0ULL;
        keep[tid] = vm;                       // K0 = valid
    }
    __syncthreads();

    for (int round = 0; round < 8192; ++round) {
        if (tid < NW) sn[tid] = 0ULL;
        if (tid == 0) chg = 0;
        __syncthreads();
        if (inLds) {
            for (int eI = tid; eI < E; eI += NTHR) {
                unsigned int p = eLds[eI];
                int r = p >> 13, c = p & 8191;
                if ((keep[r >> 6] >> (r & 63)) & 1ULL)
                    atomicOr(&sn[c >> 6], 1ULL << (c & 63));
            }
        } else {
            for (int eI = tid; eI < E; eI += NTHR) {
                unsigned int p = pairs[eI];
                int r = p >> 13, c = p & 8191;
                if ((keep[r >> 6] >> (r & 63)) & 1ULL)
                    atomicOr(&sn[c >> 6], 1ULL << (c & 63));
            }
        }
        __syncthreads();
        if (tid < NW) {
            unsigned long long nk = vm & ~sn[tid];
            if (nk != keep[tid]) { keep[tid] = nk; chg = 1; }
        }
        __syncthreads();
        if (!chg) break;                      // uniform (LDS, post-barrier)
    }

    // output: group leaders still hold {rank rr, cls bi, conf myConf}
    if (s == 0) {
        int i = i0 + e;
        float m = (float)((keep[rr >> 6] >> (rr & 63)) & 1ULL);
        float4 b = ((const float4*)box)[i];
        out[i * 5 + 0] = b.x * m;
        out[i * 5 + 1] = b.y * m;
        out[i * 5 + 2] = b.z * m;
        out[i * 5 + 3] = b.w * m;
        out[i * 5 + 4] = myConf * m;
        out[5 * N + i] = (float)bi;
        out[6 * N + i] = m;
    }
}

// ---------------- launch -------------------------------------------------
extern "C" void kernel_launch(void* const* d_in, const int* in_sizes, int n_in,
                              void* d_out, int out_size, void* d_ws, size_t ws_size,
                              hipStream_t stream) {
    const float* box    = (const float*)d_in[0];
    const float* conf   = (const float*)d_in[1];
    const float* logits = (const float*)d_in[2];
    float* out = (float*)d_out;

    char* ws = (char*)d_ws;
    float4* sbx     = (float4*)(ws + 0);                 // 128 KB
    float*  sarea   = (float*) (ws + 131072);            // 32 KB
    int*    scls    = (int*)   (ws + 163840);            // 32 KB
    int*    paircnt = (int*)   (ws + 196608);            // 4 B
    unsigned int* pairs = (unsigned int*)(ws + 262144);  // 8 MB

    void* args[] = { (void*)&box, (void*)&conf, (void*)&logits,
                     (void*)&sbx, (void*)&sarea, (void*)&scls,
                     (void*)&pairs, (void*)&paircnt, (void*)&out };
    hipLaunchCooperativeKernel(reinterpret_cast<void*>(k_fused),
                               dim3(NBLK), dim3(NTHR), args, 0, stream);
}

// Round 3
// 138.478 us; speedup vs baseline: 1.5710x; 1.5710x over previous
//
#include <hip/hip_runtime.h>
#include <stdint.h>

#define N 8192
#define NCLS 80
#define NW 128              // N/64 keep-mask words
#define PAIR_CAP (1 << 21)  // 2M pairs (8 MB) -- expected E ~ 2-5K
#define ELDS_CAP 8192       // edges staged in LDS for the fixpoint
#define NOWN 32             // elements owned per block in prepsort

// Key: ascending key == descending conf for valid (conf>0.5 => positive
// float => bit-monotonic); invalid sort last, tie-broken by index (stable).
__device__ __forceinline__ unsigned long long makeKey(float c, int idx) {
    unsigned int kb = (c > 0.5f) ? ~__float_as_uint(c) : 0xFFFFFFFFu;
    return ((unsigned long long)kb << 32) | (unsigned int)idx;
}

// ---------------- K1: block-local rank + argmax + scatter (no atomics) --
// 256 blocks x 256 thr; block owns 32 elements (8 threads each). All 8192
// keys are re-derived from conf and streamed through LDS in 8 chunks; each
// 8-thread group counts keys < its key -> exact stable rank. V computed
// redundantly per block by reduction; block 0 publishes it.
__global__ __launch_bounds__(256) void k_prepsort(
    const float* __restrict__ box,
    const float* __restrict__ conf,
    const float* __restrict__ logits,
    float4* __restrict__ sbx,
    float* __restrict__ sarea,
    int* __restrict__ scls,
    int* __restrict__ rankArr,
    int* __restrict__ clsArr,
    int* __restrict__ Vout,
    int* __restrict__ paircnt)
{
#pragma clang fp contract(off)
    __shared__ unsigned long long tile[1024];   // 8 KB key-chunk staging
    __shared__ int vpart[4];
    const int tid = threadIdx.x;
    const int bid = blockIdx.x;
    if (bid == 0 && tid == 0) *paircnt = 0;

    const int i0 = bid * NOWN;
    const int e = tid >> 3;                     // owned element 0..31
    const int s = tid & 7;                      // 8-way slice within element
    const float myConf = conf[i0 + e];
    const unsigned long long myKey = makeKey(myConf, i0 + e);

    int rr = 0;       // partial rank (this slice's count of keys < myKey)
    int vloc = 0;     // valid-count over this thread's staged confs
    for (int ch = 0; ch < 8; ++ch) {
        float4 c4 = ((const float4*)conf)[ch * 256 + tid];
        int base = ch * 1024 + tid * 4;
        tile[tid * 4 + 0] = makeKey(c4.x, base + 0);
        tile[tid * 4 + 1] = makeKey(c4.y, base + 1);
        tile[tid * 4 + 2] = makeKey(c4.z, base + 2);
        tile[tid * 4 + 3] = makeKey(c4.w, base + 3);
        vloc += (c4.x > 0.5f) + (c4.y > 0.5f) + (c4.z > 0.5f) + (c4.w > 0.5f);
        __syncthreads();
        // slice j = jj*8 + s: 8 distinct u64 addrs per wave row, broadcast
        // x8 -> conflict-free
#pragma unroll 32
        for (int jj = 0; jj < 128; ++jj)
            rr += (tile[(jj << 3) | s] < myKey) ? 1 : 0;
        __syncthreads();
    }
    // rank reduce across the 8-thread group (result lands at s==0)
    rr += __shfl_down(rr, 4, 8);
    rr += __shfl_down(rr, 2, 8);
    rr += __shfl_down(rr, 1, 8);

    // V reduce across the block (each conf counted exactly once)
    int vs = vloc;
    for (int off = 32; off; off >>= 1) vs += __shfl_down(vs, off);
    if ((tid & 63) == 0) vpart[tid >> 6] = vs;

    // argmax over 80 logits, 10 per slice-thread (first-max-wins exact:
    // strict > locally; combine prefers greater value, tie -> lower index)
    const float2* lp2 = (const float2*)(logits + (size_t)(i0 + e) * NCLS + s * 10);
    float best = -INFINITY;
    int bi = s * 10;
#pragma unroll 5
    for (int j = 0; j < 5; ++j) {
        float2 v = lp2[j];
        if (v.x > best) { best = v.x; bi = s * 10 + 2 * j; }
        if (v.y > best) { best = v.y; bi = s * 10 + 2 * j + 1; }
    }
    for (int off = 4; off; off >>= 1) {
        float ob = __shfl_down(best, off, 8);
        int oi = __shfl_down(bi, off, 8);
        if (ob > best || (ob == best && oi < bi)) { best = ob; bi = oi; }
    }
    __syncthreads();
    if (tid == 0 && bid == 0)
        *Vout = vpart[0] + vpart[1] + vpart[2] + vpart[3];

    if (s == 0) {   // group leader: publish rank/cls + scatter sorted entry
        rankArr[i0 + e] = rr;
        clsArr[i0 + e] = bi;
        float4 b = ((const float4*)box)[i0 + e];    // x, y, w, h
        float hw = b.z * 0.5f, hh = b.w * 0.5f;     // == w/2 exactly
        sbx[rr]   = make_float4(b.x - hw, b.y - hh, b.x + hw, b.y + hh);
        sarea[rr] = b.z * b.w;
        scls[rr]  = bi;
    }
}

// ---------------- K2: sparse suppression-pair extraction ----------------
__global__ __launch_bounds__(256) void k_pairs(const float4* __restrict__ sbx,
                                               const float* __restrict__ sarea,
                                               const int* __restrict__ scls,
                                               const int* __restrict__ Vcnt,
                                               unsigned int* __restrict__ pairs,
                                               int* __restrict__ paircnt) {
#pragma clang fp contract(off)
    __shared__ float4 cb[256];
    __shared__ float  ca[256];
    __shared__ int    cc[256];
    int rbase = blockIdx.x * 256;
    int cbase = blockIdx.y * 256;
    if (cbase < rbase) return;               // strictly sub-diagonal: skip
    int V = *Vcnt;
    if (rbase >= V) return;
    if (cbase >= V) return;

    int r = rbase + threadIdx.x;
    bool active = (r < V);
    float4 rb4; float rar; int rcls;
    if (active) { rb4 = sbx[r]; rar = sarea[r]; rcls = scls[r]; }

    int t = cbase + threadIdx.x;
    cb[threadIdx.x] = sbx[t];
    ca[threadIdx.x] = sarea[t];
    cc[threadIdx.x] = scls[t];
    __syncthreads();
    if (!active) return;

#pragma unroll 4
    for (int k = 0; k < 256; ++k) {
        int c = cbase + k;
        float4 c4 = cb[k];
        // exact float32 op order of the reference:
        float iw = fminf(rb4.z, c4.z) - fmaxf(rb4.x, c4.x);
        iw = fmaxf(iw, 0.0f);
        float ih = fminf(rb4.w, c4.w) - fmaxf(rb4.y, c4.y);
        ih = fmaxf(ih, 0.0f);
        float inter = iw * ih;
        float uni = rar + ca[k] - inter;
        float iou = __fdiv_rn(inter, uni);       // IEEE-rounded divide
        bool sup = (iou > 0.5f) & (cc[k] == rcls) & (c > r) & (c < V);
        if (sup) {
            int idx = atomicAdd(paircnt, 1);
            if (idx < PAIR_CAP) pairs[idx] = ((unsigned int)r << 13) | (unsigned int)c;
        }
    }
}

// ---------------- K3: greedy NMS as sparse Jacobi fixpoint --------------
// Single block (timing isolation). Edges staged in LDS; rounds pure-LDS.
// keep_{t+1}[c] = valid[c] & !exists edge r->c with keep_t[r]; edges go
// strictly up in rank (DAG) => unique fixpoint == sequential greedy scan.
__global__ __launch_bounds__(256) void k_scan(const unsigned int* __restrict__ pairs,
                                              const int* __restrict__ paircnt,
                                              const int* __restrict__ Vcnt,
                                              unsigned long long* __restrict__ keepw) {
    __shared__ unsigned long long keep[NW];
    __shared__ unsigned long long sn[NW];
    __shared__ unsigned int eLds[ELDS_CAP];     // 32 KB edge staging
    __shared__ int chg;
    const int tid = threadIdx.x;
    const int V = *Vcnt;
    int E = *paircnt; if (E > PAIR_CAP) E = PAIR_CAP;
    const bool inLds = (E <= ELDS_CAP);
    if (inLds)
        for (int eI = tid; eI < E; eI += 256) eLds[eI] = pairs[eI];

    const int fullw = V >> 6, remb = V & 63;
    unsigned long long vm = 0ULL;
    if (tid < NW) {
        vm = (tid < fullw) ? ~0ULL
           : (tid == fullw && remb) ? ((1ULL << remb) - 1ULL) : 0ULL;
        keep[tid] = vm;                       // K0 = valid
    }
    __syncthreads();

    for (int round = 0; round < 8192; ++round) {
        if (tid < NW) sn[tid] = 0ULL;
        if (tid == 0) chg = 0;
        __syncthreads();
        if (inLds) {
            for (int eI = tid; eI < E; eI += 256) {
                unsigned int p = eLds[eI];
                int r = p >> 13, c = p & 8191;
                if ((keep[r >> 6] >> (r & 63)) & 1ULL)
                    atomicOr(&sn[c >> 6], 1ULL << (c & 63));
            }
        } else {
            for (int eI = tid; eI < E; eI += 256) {
                unsigned int p = pairs[eI];
                int r = p >> 13, c = p & 8191;
                if ((keep[r >> 6] >> (r & 63)) & 1ULL)
                    atomicOr(&sn[c >> 6], 1ULL << (c & 63));
            }
        }
        __syncthreads();
        if (tid < NW) {
            unsigned long long nk = vm & ~sn[tid];
            if (nk != keep[tid]) { keep[tid] = nk; chg = 1; }
        }
        __syncthreads();
        if (!chg) break;                      // uniform (LDS, post-barrier)
    }
    if (tid < NW) keepw[tid] = keep[tid];
}

// ---------------- K4: outputs -------------------------------------------
__global__ __launch_bounds__(256) void k_out(const float* __restrict__ box,
                                             const float* __restrict__ conf,
                                             const int* __restrict__ clsArr,
                                             const int* __restrict__ rankArr,
                                             const unsigned long long* __restrict__ keepw,
                                             float* __restrict__ out) {
    int i = blockIdx.x * blockDim.x + threadIdx.x;
    if (i >= N) return;
    int r = rankArr[i];
    float m = (float)((keepw[r >> 6] >> (r & 63)) & 1ULL);
    float4 b = ((const float4*)box)[i];
    out[i * 5 + 0] = b.x * m;
    out[i * 5 + 1] = b.y * m;
    out[i * 5 + 2] = b.z * m;
    out[i * 5 + 3] = b.w * m;
    out[i * 5 + 4] = conf[i] * m;
    out[5 * N + i] = (float)clsArr[i];
    out[6 * N + i] = m;
}

// ---------------- launch -------------------------------------------------
extern "C" void kernel_launch(void* const* d_in, const int* in_sizes, int n_in,
                              void* d_out, int out_size, void* d_ws, size_t ws_size,
                              hipStream_t stream) {
    const float* box    = (const float*)d_in[0];
    const float* conf   = (const float*)d_in[1];
    const float* logits = (const float*)d_in[2];
    float* out = (float*)d_out;

    char* ws = (char*)d_ws;
    float4* sbx     = (float4*)(ws + 0);                 // 128 KB
    float*  sarea   = (float*) (ws + 131072);            // 32 KB
    int*    scls    = (int*)   (ws + 163840);            // 32 KB
    int*    rankArr = (int*)   (ws + 196608);            // 32 KB
    int*    clsArr  = (int*)   (ws + 229376);            // 32 KB
    int*    Vcnt    = (int*)   (ws + 262144);            // 4 B
    int*    paircnt = (int*)   (ws + 262208);            // 4 B
    unsigned long long* keepw = (unsigned long long*)(ws + 262272); // 1 KB
    unsigned int* pairs = (unsigned int*)(ws + 327680);  // 8 MB

    k_prepsort<<<N / NOWN, 256, 0, stream>>>(box, conf, logits, sbx, sarea,
                                             scls, rankArr, clsArr, Vcnt, paircnt);
    k_pairs<<<dim3(N / 256, N / 256), 256, 0, stream>>>(sbx, sarea, scls, Vcnt,
                                                        pairs, paircnt);
    k_scan<<<1, 256, 0, stream>>>(pairs, paircnt, Vcnt, keepw);
    k_out<<<N / 256, 256, 0, stream>>>(box, conf, clsArr, rankArr, keepw, out);
}

// Round 4
// 118.601 us; speedup vs baseline: 1.8343x; 1.1676x over previous
//
#include <hip/hip_runtime.h>
#include <stdint.h>

#define N 8192
#define NCLS 80
#define NW 128              // N/64 keep-mask words
#define PAIR_CAP (1 << 20)  // 1M pairs (4 MB) -- expected E ~ 2K
#define ELDS_CAP 8192       // edges staged in LDS for the fixpoint
#define NOWN 32             // elements owned per block in prepsort
#define CCAP 512            // per-class bucket capacity (expected ~51)

// Key: ascending key == descending conf for valid (conf>0.5 => positive
// float => bit-monotonic); invalid sort last, tie-broken by index (stable).
__device__ __forceinline__ unsigned long long makeKey(float c, int idx) {
    unsigned int kb = (c > 0.5f) ? ~__float_as_uint(c) : 0xFFFFFFFFu;
    return ((unsigned long long)kb << 32) | (unsigned int)idx;
}

// ---------------- K1: block-local rank + argmax + class-bucket scatter --
// 256 blocks x 256 thr; block owns 32 elements (8 threads each). All 8192
// keys re-derived from conf, streamed through LDS in 8 chunks; each
// 8-thread group counts keys < its key -> exact stable rank. Valid boxes
// are scattered into per-class buckets (order within bucket irrelevant:
// pair extraction emits edges by rank). ccount/paircnt pre-zeroed by
// hipMemsetAsync.
__global__ __launch_bounds__(256) void k_prepsort(
    const float* __restrict__ box,
    const float* __restrict__ conf,
    const float* __restrict__ logits,
    int* __restrict__ rankArr,
    int* __restrict__ clsArr,
    int* __restrict__ Vout,
    int* __restrict__ ccount,
    int* __restrict__ cR,
    float* __restrict__ cA,
    float4* __restrict__ cB)
{
#pragma clang fp contract(off)
    __shared__ unsigned long long tile[1024];   // 8 KB key-chunk staging
    __shared__ int vpart[4];
    const int tid = threadIdx.x;
    const int bid = blockIdx.x;

    const int i0 = bid * NOWN;
    const int e = tid >> 3;                     // owned element 0..31
    const int s = tid & 7;                      // 8-way slice within element
    const float myConf = conf[i0 + e];
    const unsigned long long myKey = makeKey(myConf, i0 + e);

    int rr = 0;       // partial rank (this slice's count of keys < myKey)
    int vloc = 0;     // valid-count over this thread's staged confs
    for (int ch = 0; ch < 8; ++ch) {
        float4 c4 = ((const float4*)conf)[ch * 256 + tid];
        int base = ch * 1024 + tid * 4;
        tile[tid * 4 + 0] = makeKey(c4.x, base + 0);
        tile[tid * 4 + 1] = makeKey(c4.y, base + 1);
        tile[tid * 4 + 2] = makeKey(c4.z, base + 2);
        tile[tid * 4 + 3] = makeKey(c4.w, base + 3);
        vloc += (c4.x > 0.5f) + (c4.y > 0.5f) + (c4.z > 0.5f) + (c4.w > 0.5f);
        __syncthreads();
        // slice j = jj*8 + s: 8 distinct u64 addrs per wave row (broadcast
        // x8) on 8 distinct bank-pairs -> conflict-free
#pragma unroll 32
        for (int jj = 0; jj < 128; ++jj)
            rr += (tile[(jj << 3) | s] < myKey) ? 1 : 0;
        __syncthreads();
    }
    // rank reduce across the 8-thread group (result lands at s==0)
    rr += __shfl_down(rr, 4, 8);
    rr += __shfl_down(rr, 2, 8);
    rr += __shfl_down(rr, 1, 8);

    // V reduce across the block (each conf counted exactly once)
    int vs = vloc;
    for (int off = 32; off; off >>= 1) vs += __shfl_down(vs, off);
    if ((tid & 63) == 0) vpart[tid >> 6] = vs;

    // argmax over 80 logits, 10 per slice-thread (first-max-wins exact:
    // strict > locally; combine prefers greater value, tie -> lower index)
    const float2* lp2 = (const float2*)(logits + (size_t)(i0 + e) * NCLS + s * 10);
    float best = -INFINITY;
    int bi = s * 10;
#pragma unroll 5
    for (int j = 0; j < 5; ++j) {
        float2 v = lp2[j];
        if (v.x > best) { best = v.x; bi = s * 10 + 2 * j; }
        if (v.y > best) { best = v.y; bi = s * 10 + 2 * j + 1; }
    }
    for (int off = 4; off; off >>= 1) {
        float ob = __shfl_down(best, off, 8);
        int oi = __shfl_down(bi, off, 8);
        if (ob > best || (ob == best && oi < bi)) { best = ob; bi = oi; }
    }
    __syncthreads();
    if (tid == 0 && bid == 0)
        *Vout = vpart[0] + vpart[1] + vpart[2] + vpart[3];

    if (s == 0) {   // group leader: publish rank/cls; bucket valid boxes
        rankArr[i0 + e] = rr;
        clsArr[i0 + e] = bi;
        if (myConf > 0.5f) {
            int pos = atomicAdd(&ccount[bi], 1);
            if (pos < CCAP) {
                float4 b = ((const float4*)box)[i0 + e];    // x, y, w, h
                float hw = b.z * 0.5f, hh = b.w * 0.5f;     // == w/2 exactly
                int o = bi * CCAP + pos;
                cR[o] = rr;
                cA[o] = b.z * b.w;
                cB[o] = make_float4(b.x - hw, b.y - hh, b.x + hw, b.y + hh);
            }
        }
    }
}

// ---------------- K2: within-class all-pairs suppression edges ----------
// One block per class (~51 boxes -> ~2.6K pair checks). For each unordered
// pair with IoU>thr, emit edge (min_rank -> max_rank). min/max/+ are
// commutative in fp32, so pair order gives bit-identical IoU to the
// reference's iou[i][j]; __fdiv_rn matches the reference divide.
__global__ __launch_bounds__(256) void k_pairs2(const int* __restrict__ ccount,
                                                const int* __restrict__ cR,
                                                const float* __restrict__ cA,
                                                const float4* __restrict__ cB,
                                                unsigned int* __restrict__ pairs,
                                                int* __restrict__ paircnt) {
#pragma clang fp contract(off)
    __shared__ float4 lb[CCAP];
    __shared__ float  la[CCAP];
    __shared__ int    lr[CCAP];
    const int tid = threadIdx.x;
    const int cls = blockIdx.x;
    int n = ccount[cls]; if (n > CCAP) n = CCAP;
    if (n < 2) return;

    for (int j = tid; j < n; j += 256) {
        int o = cls * CCAP + j;
        lb[j] = cB[o];
        la[j] = cA[o];
        lr[j] = cR[o];
    }
    __syncthreads();

    const int total = n * n;
    for (int t = tid; t < total; t += 256) {
        int a = t / n, b = t - a * n;
        if (b > a) {
            float4 A = lb[a], B = lb[b];
            // exact float32 op order of the reference:
            float iw = fminf(A.z, B.z) - fmaxf(A.x, B.x);
            iw = fmaxf(iw, 0.0f);
            float ih = fminf(A.w, B.w) - fmaxf(A.y, B.y);
            ih = fmaxf(ih, 0.0f);
            float inter = iw * ih;
            float uni = la[a] + la[b] - inter;
            float iou = __fdiv_rn(inter, uni);   // IEEE-rounded divide
            if (iou > 0.5f) {
                int ra = lr[a], rb = lr[b];
                unsigned int rlo = (ra < rb) ? ra : rb;
                unsigned int rhi = (ra < rb) ? rb : ra;
                int idx = atomicAdd(paircnt, 1);
                if (idx < PAIR_CAP) pairs[idx] = (rlo << 13) | rhi;
            }
        }
    }
}

// ---------------- K3: greedy NMS as sparse Jacobi fixpoint --------------
// keep_{t+1}[c] = valid[c] & !exists edge r->c with keep_t[r]; edges go
// strictly up in rank (DAG) => unique fixpoint == sequential greedy scan.
__global__ __launch_bounds__(256) void k_scan(const unsigned int* __restrict__ pairs,
                                              const int* __restrict__ paircnt,
                                              const int* __restrict__ Vcnt,
                                              unsigned long long* __restrict__ keepw) {
    __shared__ unsigned long long keep[NW];
    __shared__ unsigned long long sn[NW];
    __shared__ unsigned int eLds[ELDS_CAP];     // 32 KB edge staging
    __shared__ int chg;
    const int tid = threadIdx.x;
    const int V = *Vcnt;
    int E = *paircnt; if (E > PAIR_CAP) E = PAIR_CAP;
    const bool inLds = (E <= ELDS_CAP);
    if (inLds)
        for (int eI = tid; eI < E; eI += 256) eLds[eI] = pairs[eI];

    const int fullw = V >> 6, remb = V & 63;
    unsigned long long vm = 0ULL;
    if (tid < NW) {
        vm = (tid < fullw) ? ~0ULL
           : (tid == fullw && remb) ? ((1ULL << remb) - 1ULL) : 0ULL;
        keep[tid] = vm;                       // K0 = valid
    }
    __syncthreads();

    for (int round = 0; round < 8192; ++round) {
        if (tid < NW) sn[tid] = 0ULL;
        if (tid == 0) chg = 0;
        __syncthreads();
        if (inLds) {
            for (int eI = tid; eI < E; eI += 256) {
                unsigned int p = eLds[eI];
                int r = p >> 13, c = p & 8191;
                if ((keep[r >> 6] >> (r & 63)) & 1ULL)
                    atomicOr(&sn[c >> 6], 1ULL << (c & 63));
            }
        } else {
            for (int eI = tid; eI < E; eI += 256) {
                unsigned int p = pairs[eI];
                int r = p >> 13, c = p & 8191;
                if ((keep[r >> 6] >> (r & 63)) & 1ULL)
                    atomicOr(&sn[c >> 6], 1ULL << (c & 63));
            }
        }
        __syncthreads();
        if (tid < NW) {
            unsigned long long nk = vm & ~sn[tid];
            if (nk != keep[tid]) { keep[tid] = nk; chg = 1; }
        }
        __syncthreads();
        if (!chg) break;                      // uniform (LDS, post-barrier)
    }
    if (tid < NW) keepw[tid] = keep[tid];
}

// ---------------- K4: outputs -------------------------------------------
__global__ __launch_bounds__(256) void k_out(const float* __restrict__ box,
                                             const float* __restrict__ conf,
                                             const int* __restrict__ clsArr,
                                             const int* __restrict__ rankArr,
                                             const unsigned long long* __restrict__ keepw,
                                             float* __restrict__ out) {
    int i = blockIdx.x * blockDim.x + threadIdx.x;
    if (i >= N) return;
    int r = rankArr[i];
    float m = (float)((keepw[r >> 6] >> (r & 63)) & 1ULL);
    float4 b = ((const float4*)box)[i];
    out[i * 5 + 0] = b.x * m;
    out[i * 5 + 1] = b.y * m;
    out[i * 5 + 2] = b.z * m;
    out[i * 5 + 3] = b.w * m;
    out[i * 5 + 4] = conf[i] * m;
    out[5 * N + i] = (float)clsArr[i];
    out[6 * N + i] = m;
}

// ---------------- launch -------------------------------------------------
extern "C" void kernel_launch(void* const* d_in, const int* in_sizes, int n_in,
                              void* d_out, int out_size, void* d_ws, size_t ws_size,
                              hipStream_t stream) {
    const float* box    = (const float*)d_in[0];
    const float* conf   = (const float*)d_in[1];
    const float* logits = (const float*)d_in[2];
    float* out = (float*)d_out;

    char* ws = (char*)d_ws;
    int*    rankArr = (int*)   (ws + 0);                 // 32 KB
    int*    clsArr  = (int*)   (ws + 32768);             // 32 KB
    int*    Vcnt    = (int*)   (ws + 65536);             // 4 B
    int*    paircnt = (int*)   (ws + 65600);             // 4 B   (zeroed)
    int*    ccount  = (int*)   (ws + 65604);             // 320 B (zeroed)
    unsigned long long* keepw = (unsigned long long*)(ws + 66560);  // 1 KB
    int*    cR      = (int*)   (ws + 131072);            // 160 KB
    float*  cA      = (float*) (ws + 294912);            // 160 KB
    float4* cB      = (float4*)(ws + 458752);            // 640 KB
    unsigned int* pairs = (unsigned int*)(ws + 1114112); // 4 MB

    hipMemsetAsync(ws + 65600, 0, 4 + NCLS * 4, stream); // paircnt + ccount

    k_prepsort<<<N / NOWN, 256, 0, stream>>>(box, conf, logits, rankArr,
                                             clsArr, Vcnt, ccount, cR, cA, cB);
    k_pairs2<<<NCLS, 256, 0, stream>>>(ccount, cR, cA, cB, pairs, paircnt);
    k_scan<<<1, 256, 0, stream>>>(pairs, paircnt, Vcnt, keepw);
    k_out<<<N / 256, 256, 0, stream>>>(box, conf, clsArr, rankArr, keepw, out);
}

// Round 5
// 108.638 us; speedup vs baseline: 2.0025x; 1.0917x over previous
//
#include <hip/hip_runtime.h>
#include <stdint.h>

#define N 8192
#define NCLS 80
#define NW 128              // N/64 keep-mask words
#define PAIR_CAP (1 << 20)  // 1M pairs (4 MB) -- expected E ~ 2K
#define ELDS_CAP 8192       // edges staged in LDS for the fixpoint
#define NOWN 32             // elements owned per block in prepsort
#define CCAP 256            // per-class member capacity (expected ~51)

// Key: ascending key == descending conf for valid (conf>0.5 => positive
// float => bit-monotonic); invalid sort last, tie-broken by index (stable).
__device__ __forceinline__ unsigned long long makeKey(float c, int idx) {
    unsigned int kb = (c > 0.5f) ? ~__float_as_uint(c) : 0xFFFFFFFFu;
    return ((unsigned long long)kb << 32) | (unsigned int)idx;
}

// ---------------- K1: block-local rank + argmax + scatter (no atomics) --
// 256 blocks x 256 thr; block owns 32 elements (8 threads each). All 8192
// keys re-derived from conf, streamed through LDS in 8 chunks; each
// 8-thread group counts keys < its key -> exact stable rank. Valid boxes
// scatter by rank (ranks 0..V-1 are exactly the valid boxes). paircnt is
// zeroed here (no other writer until next dispatch).
__global__ __launch_bounds__(256) void k_prepsort(
    const float* __restrict__ box,
    const float* __restrict__ conf,
    const float* __restrict__ logits,
    float4* __restrict__ sbx,
    float* __restrict__ sarea,
    int* __restrict__ scls,
    int* __restrict__ rankArr,
    int* __restrict__ clsArr,
    int* __restrict__ Vout,
    int* __restrict__ paircnt)
{
#pragma clang fp contract(off)
    __shared__ unsigned long long tile[1024];   // 8 KB key-chunk staging
    __shared__ int vpart[4];
    const int tid = threadIdx.x;
    const int bid = blockIdx.x;
    if (bid == 0 && tid == 0) *paircnt = 0;

    const int i0 = bid * NOWN;
    const int e = tid >> 3;                     // owned element 0..31
    const int s = tid & 7;                      // 8-way slice within element
    const float myConf = conf[i0 + e];
    const unsigned long long myKey = makeKey(myConf, i0 + e);

    int rr = 0;       // partial rank (this slice's count of keys < myKey)
    int vloc = 0;     // valid-count over this thread's staged confs
    for (int ch = 0; ch < 8; ++ch) {
        float4 c4 = ((const float4*)conf)[ch * 256 + tid];
        int base = ch * 1024 + tid * 4;
        tile[tid * 4 + 0] = makeKey(c4.x, base + 0);
        tile[tid * 4 + 1] = makeKey(c4.y, base + 1);
        tile[tid * 4 + 2] = makeKey(c4.z, base + 2);
        tile[tid * 4 + 3] = makeKey(c4.w, base + 3);
        vloc += (c4.x > 0.5f) + (c4.y > 0.5f) + (c4.z > 0.5f) + (c4.w > 0.5f);
        __syncthreads();
        // slice j = jj*8 + s: 8 distinct u64 addrs per wave row (broadcast
        // x8) on 8 distinct bank-pairs -> conflict-free
#pragma unroll 32
        for (int jj = 0; jj < 128; ++jj)
            rr += (tile[(jj << 3) | s] < myKey) ? 1 : 0;
        __syncthreads();
    }
    // rank reduce across the 8-thread group (result lands at s==0)
    rr += __shfl_down(rr, 4, 8);
    rr += __shfl_down(rr, 2, 8);
    rr += __shfl_down(rr, 1, 8);

    // V reduce across the block (each conf counted exactly once)
    int vs = vloc;
    for (int off = 32; off; off >>= 1) vs += __shfl_down(vs, off);
    if ((tid & 63) == 0) vpart[tid >> 6] = vs;

    // argmax over 80 logits, 10 per slice-thread (first-max-wins exact:
    // strict > locally; combine prefers greater value, tie -> lower index)
    const float2* lp2 = (const float2*)(logits + (size_t)(i0 + e) * NCLS + s * 10);
    float best = -INFINITY;
    int bi = s * 10;
#pragma unroll 5
    for (int j = 0; j < 5; ++j) {
        float2 v = lp2[j];
        if (v.x > best) { best = v.x; bi = s * 10 + 2 * j; }
        if (v.y > best) { best = v.y; bi = s * 10 + 2 * j + 1; }
    }
    for (int off = 4; off; off >>= 1) {
        float ob = __shfl_down(best, off, 8);
        int oi = __shfl_down(bi, off, 8);
        if (ob > best || (ob == best && oi < bi)) { best = ob; bi = oi; }
    }
    __syncthreads();
    if (tid == 0 && bid == 0)
        *Vout = vpart[0] + vpart[1] + vpart[2] + vpart[3];

    if (s == 0) {   // group leader: publish rank/cls + scatter sorted entry
        rankArr[i0 + e] = rr;
        clsArr[i0 + e] = bi;
        float4 b = ((const float4*)box)[i0 + e];    // x, y, w, h
        float hw = b.z * 0.5f, hh = b.w * 0.5f;     // == w/2 exactly
        sbx[rr]   = make_float4(b.x - hw, b.y - hh, b.x + hw, b.y + hh);
        sarea[rr] = b.z * b.w;
        scls[rr]  = bi;
    }
}

// ---------------- K2: within-class all-pairs suppression edges ----------
// One block per class. Block c scans scls[0..V) (16 KB stream, L2-
// broadcast across the 80 blocks), collects its ~51 member ranks into
// LDS, stages their boxes, then all-pairs. For each unordered pair with
// IoU>thr emits edge (min_rank -> max_rank). fminf/fmaxf/+ are
// commutative in fp32 => bit-identical IoU to the reference's iou[i][j];
// __fdiv_rn matches the reference divide. No pre-zeroed globals needed.
__global__ __launch_bounds__(256) void k_pairs2(const float4* __restrict__ sbx,
                                                const float* __restrict__ sarea,
                                                const int* __restrict__ scls,
                                                const int* __restrict__ Vcnt,
                                                unsigned int* __restrict__ pairs,
                                                int* __restrict__ paircnt) {
#pragma clang fp contract(off)
    __shared__ unsigned short mlist[CCAP];
    __shared__ float4 mb[CCAP];
    __shared__ float  ma[CCAP];
    __shared__ int mcnt;
    const int tid = threadIdx.x;
    const int cls = blockIdx.x;
    const int V = *Vcnt;
    if (tid == 0) mcnt = 0;
    __syncthreads();

    for (int r = tid; r < V; r += 256)
        if (scls[r] == cls) {
            int p = atomicAdd(&mcnt, 1);
            if (p < CCAP) mlist[p] = (unsigned short)r;
        }
    __syncthreads();
    int n = mcnt; if (n > CCAP) n = CCAP;
    if (n < 2) return;

    for (int j = tid; j < n; j += 256) {
        int r = mlist[j];
        mb[j] = sbx[r];
        ma[j] = sarea[r];
    }
    __syncthreads();

    const int total = n * n;
    for (int t = tid; t < total; t += 256) {
        int a = t / n, b = t - a * n;
        if (b > a) {
            float4 A = mb[a], B = mb[b];
            // exact float32 op order of the reference:
            float iw = fminf(A.z, B.z) - fmaxf(A.x, B.x);
            iw = fmaxf(iw, 0.0f);
            float ih = fminf(A.w, B.w) - fmaxf(A.y, B.y);
            ih = fmaxf(ih, 0.0f);
            float inter = iw * ih;
            float uni = ma[a] + ma[b] - inter;
            float iou = __fdiv_rn(inter, uni);   // IEEE-rounded divide
            if (iou > 0.5f) {
                int ra = mlist[a], rb = mlist[b];
                unsigned int rlo = (ra < rb) ? (unsigned int)ra : (unsigned int)rb;
                unsigned int rhi = (ra < rb) ? (unsigned int)rb : (unsigned int)ra;
                int idx = atomicAdd(paircnt, 1);
                if (idx < PAIR_CAP) pairs[idx] = (rlo << 13) | rhi;
            }
        }
    }
}

// ---------------- K3: fixpoint + outputs (fused) ------------------------
// 32 blocks x 256. Each block redundantly runs the Jacobi fixpoint over
// the (identical) edge list -- deterministic unique fixpoint == greedy
// scan (edges strictly increase rank => DAG) -- then writes its own 256
// output rows from LDS. Removes the scan->out boundary and keepw array.
__global__ __launch_bounds__(256) void k_scanout(const unsigned int* __restrict__ pairs,
                                                 const int* __restrict__ paircnt,
                                                 const int* __restrict__ Vcnt,
                                                 const float* __restrict__ box,
                                                 const float* __restrict__ conf,
                                                 const int* __restrict__ clsArr,
                                                 const int* __restrict__ rankArr,
                                                 float* __restrict__ out) {
    __shared__ unsigned long long keep[NW];
    __shared__ unsigned long long sn[NW];
    __shared__ unsigned int eLds[ELDS_CAP];     // 32 KB edge staging
    __shared__ int chg;
    const int tid = threadIdx.x;
    const int V = *Vcnt;
    int E = *paircnt; if (E > PAIR_CAP) E = PAIR_CAP;
    const bool inLds = (E <= ELDS_CAP);
    if (inLds)
        for (int eI = tid; eI < E; eI += 256) eLds[eI] = pairs[eI];

    const int fullw = V >> 6, remb = V & 63;
    unsigned long long vm = 0ULL;
    if (tid < NW) {
        vm = (tid < fullw) ? ~0ULL
           : (tid == fullw && remb) ? ((1ULL << remb) - 1ULL) : 0ULL;
        keep[tid] = vm;                       // K0 = valid
    }
    __syncthreads();

    for (int round = 0; round < 8192; ++round) {
        if (tid < NW) sn[tid] = 0ULL;
        if (tid == 0) chg = 0;
        __syncthreads();
        if (inLds) {
            for (int eI = tid; eI < E; eI += 256) {
                unsigned int p = eLds[eI];
                int r = p >> 13, c = p & 8191;
                if ((keep[r >> 6] >> (r & 63)) & 1ULL)
                    atomicOr(&sn[c >> 6], 1ULL << (c & 63));
            }
        } else {
            for (int eI = tid; eI < E; eI += 256) {
                unsigned int p = pairs[eI];
                int r = p >> 13, c = p & 8191;
                if ((keep[r >> 6] >> (r & 63)) & 1ULL)
                    atomicOr(&sn[c >> 6], 1ULL << (c & 63));
            }
        }
        __syncthreads();
        if (tid < NW) {
            unsigned long long nk = vm & ~sn[tid];
            if (nk != keep[tid]) { keep[tid] = nk; chg = 1; }
        }
        __syncthreads();
        if (!chg) break;                      // uniform (LDS, post-barrier)
    }

    // outputs for this block's 256 elements (keep read from own LDS)
    const int i = blockIdx.x * 256 + tid;
    const int r = rankArr[i];
    const float m = (float)((keep[r >> 6] >> (r & 63)) & 1ULL);
    float4 b = ((const float4*)box)[i];
    out[i * 5 + 0] = b.x * m;
    out[i * 5 + 1] = b.y * m;
    out[i * 5 + 2] = b.z * m;
    out[i * 5 + 3] = b.w * m;
    out[i * 5 + 4] = conf[i] * m;
    out[5 * N + i] = (float)clsArr[i];
    out[6 * N + i] = m;
}

// ---------------- launch -------------------------------------------------
extern "C" void kernel_launch(void* const* d_in, const int* in_sizes, int n_in,
                              void* d_out, int out_size, void* d_ws, size_t ws_size,
                              hipStream_t stream) {
    const float* box    = (const float*)d_in[0];
    const float* conf   = (const float*)d_in[1];
    const float* logits = (const float*)d_in[2];
    float* out = (float*)d_out;

    char* ws = (char*)d_ws;
    int*    rankArr = (int*)   (ws + 0);                 // 32 KB
    int*    clsArr  = (int*)   (ws + 32768);             // 32 KB
    int*    Vcnt    = (int*)   (ws + 65536);             // 4 B
    int*    paircnt = (int*)   (ws + 65600);             // 4 B
    float4* sbx     = (float4*)(ws + 131072);            // 128 KB
    float*  sarea   = (float*) (ws + 262144);            // 32 KB
    int*    scls    = (int*)   (ws + 294912);            // 32 KB
    unsigned int* pairs = (unsigned int*)(ws + 393216);  // 4 MB

    k_prepsort<<<N / NOWN, 256, 0, stream>>>(box, conf, logits, sbx, sarea,
                                             scls, rankArr, clsArr, Vcnt, paircnt);
    k_pairs2<<<NCLS, 256, 0, stream>>>(sbx, sarea, scls, Vcnt, pairs, paircnt);
    k_scanout<<<N / 256, 256, 0, stream>>>(pairs, paircnt, Vcnt, box, conf,
                                           clsArr, rankArr, out);
}

// Round 6
// 98.216 us; speedup vs baseline: 2.2150x; 1.1061x over previous
//
#include <hip/hip_runtime.h>
#include <stdint.h>

#define N 8192
#define NCLS 80
#define NW 128              // N/64 keep-mask words
#define PAIR_CAP (1 << 20)  // 1M pairs (4 MB) -- expected E ~ 2K
#define ELDS_CAP 8192       // edges staged in LDS for the fixpoint
#define NOWN 16             // elements owned per block in prepsort
#define CCAP 256            // per-class member capacity (expected ~51)

// Key: ascending key == descending conf for valid (conf>0.5 => positive
// float => bit-monotonic); invalid sort last, tie-broken by index (stable).
__device__ __forceinline__ unsigned long long makeKey(float c, int idx) {
    unsigned int kb = (c > 0.5f) ? ~__float_as_uint(c) : 0xFFFFFFFFu;
    return ((unsigned long long)kb << 32) | (unsigned int)idx;
}

// ---------------- K1: block-local rank + argmax + scatter (no atomics) --
// 512 blocks x 256 thr (2 blocks/CU = 2 waves/SIMD for latency hiding);
// block owns 16 elements (16 threads each). All 8192 keys re-derived from
// conf, streamed through LDS in 8 chunks; each 16-thread group counts
// keys < its key -> exact stable rank (512 compares/thread). Per wave
// instruction: 16 distinct u64 LDS addrs x 4-way broadcast -> all 32
// banks exactly once, conflict-free. Logits argmax is float4-cooperative
// (contiguous 256B+64B per element). paircnt zeroed here.
__global__ __launch_bounds__(256) void k_prepsort(
    const float* __restrict__ box,
    const float* __restrict__ conf,
    const float* __restrict__ logits,
    float4* __restrict__ sbx,
    float* __restrict__ sarea,
    int* __restrict__ scls,
    int* __restrict__ rankArr,
    int* __restrict__ clsArr,
    int* __restrict__ Vout,
    int* __restrict__ paircnt)
{
#pragma clang fp contract(off)
    __shared__ unsigned long long tile[1024];   // 8 KB key-chunk staging
    __shared__ int vpart[4];
    const int tid = threadIdx.x;
    const int bid = blockIdx.x;
    if (bid == 0 && tid == 0) *paircnt = 0;

    const int i0 = bid * NOWN;
    const int e = tid >> 4;                     // owned element 0..15
    const int s = tid & 15;                     // 16-way slice within element
    const float myConf = conf[i0 + e];
    const unsigned long long myKey = makeKey(myConf, i0 + e);

    int rr = 0;       // partial rank (this slice's count of keys < myKey)
    int vloc = 0;     // valid-count over this thread's staged confs
    for (int ch = 0; ch < 8; ++ch) {
        float4 c4 = ((const float4*)conf)[ch * 256 + tid];
        int base = ch * 1024 + tid * 4;
        tile[tid * 4 + 0] = makeKey(c4.x, base + 0);
        tile[tid * 4 + 1] = makeKey(c4.y, base + 1);
        tile[tid * 4 + 2] = makeKey(c4.z, base + 2);
        tile[tid * 4 + 3] = makeKey(c4.w, base + 3);
        vloc += (c4.x > 0.5f) + (c4.y > 0.5f) + (c4.z > 0.5f) + (c4.w > 0.5f);
        __syncthreads();
        // slice j = jj*16 + s: byte offsets jj*128 + s*8 -> banks (2s,2s+1)
        // -> 32 banks once per instruction, 4-way broadcast, conflict-free
#pragma unroll 32
        for (int jj = 0; jj < 64; ++jj)
            rr += (tile[(jj << 4) | s] < myKey) ? 1 : 0;
        __syncthreads();
    }
    // rank reduce across the 16-thread group (result lands at s==0)
    rr += __shfl_down(rr, 8, 16);
    rr += __shfl_down(rr, 4, 16);
    rr += __shfl_down(rr, 2, 16);
    rr += __shfl_down(rr, 1, 16);

    // V reduce across the block (each conf counted exactly once per block)
    int vs = vloc;
    for (int off = 32; off; off >>= 1) vs += __shfl_down(vs, off);
    if ((tid & 63) == 0) vpart[tid >> 6] = vs;

    // argmax over 80 logits, float4-cooperative: thread s takes float4 j=s
    // (words 4s..4s+3) and, if s<4, j=16+s (words 64+4s..67+4s). Within-
    // thread scan is ascending-index with strict > (first-max-wins); the
    // combine prefers greater value, tie -> lower index => exact argmax.
    {
        const float4* lp4 = (const float4*)(logits + (size_t)(i0 + e) * NCLS);
        float best = -INFINITY;
        int bi = 0;
        float4 v = lp4[s];
        int b0 = 4 * s;
        best = v.x; bi = b0;
        if (v.y > best) { best = v.y; bi = b0 + 1; }
        if (v.z > best) { best = v.z; bi = b0 + 2; }
        if (v.w > best) { best = v.w; bi = b0 + 3; }
        if (s < 4) {
            float4 w = lp4[16 + s];
            int b1 = 64 + 4 * s;
            if (w.x > best) { best = w.x; bi = b1; }
            if (w.y > best) { best = w.y; bi = b1 + 1; }
            if (w.z > best) { best = w.z; bi = b1 + 2; }
            if (w.w > best) { best = w.w; bi = b1 + 3; }
        }
        for (int off = 8; off; off >>= 1) {
            float ob = __shfl_down(best, off, 16);
            int oi = __shfl_down(bi, off, 16);
            if (ob > best || (ob == best && oi < bi)) { best = ob; bi = oi; }
        }
        __syncthreads();
        if (tid == 0 && bid == 0)
            *Vout = vpart[0] + vpart[1] + vpart[2] + vpart[3];

        if (s == 0) {   // group leader: publish rank/cls + scatter entry
            rankArr[i0 + e] = rr;
            clsArr[i0 + e] = bi;
            float4 b = ((const float4*)box)[i0 + e];    // x, y, w, h
            float hw = b.z * 0.5f, hh = b.w * 0.5f;     // == w/2 exactly
            sbx[rr]   = make_float4(b.x - hw, b.y - hh, b.x + hw, b.y + hh);
            sarea[rr] = b.z * b.w;
            scls[rr]  = bi;
        }
    }
}

// ---------------- K2: within-class all-pairs suppression edges ----------
// One block per class. Block c scans scls[0..V) (16 KB stream, L2-
// broadcast across the 80 blocks), collects its ~51 member ranks into
// LDS, stages their boxes, then all-pairs. For each unordered pair with
// IoU>thr emits edge (min_rank -> max_rank). fminf/fmaxf/+ are
// commutative in fp32 => bit-identical IoU to the reference's iou[i][j];
// __fdiv_rn matches the reference divide. No pre-zeroed globals needed.
__global__ __launch_bounds__(256) void k_pairs2(const float4* __restrict__ sbx,
                                                const float* __restrict__ sarea,
                                                const int* __restrict__ scls,
                                                const int* __restrict__ Vcnt,
                                                unsigned int* __restrict__ pairs,
                                                int* __restrict__ paircnt) {
#pragma clang fp contract(off)
    __shared__ unsigned short mlist[CCAP];
    __shared__ float4 mb[CCAP];
    __shared__ float  ma[CCAP];
    __shared__ int mcnt;
    const int tid = threadIdx.x;
    const int cls = blockIdx.x;
    const int V = *Vcnt;
    if (tid == 0) mcnt = 0;
    __syncthreads();

    for (int r = tid; r < V; r += 256)
        if (scls[r] == cls) {
            int p = atomicAdd(&mcnt, 1);
            if (p < CCAP) mlist[p] = (unsigned short)r;
        }
    __syncthreads();
    int n = mcnt; if (n > CCAP) n = CCAP;
    if (n < 2) return;

    for (int j = tid; j < n; j += 256) {
        int r = mlist[j];
        mb[j] = sbx[r];
        ma[j] = sarea[r];
    }
    __syncthreads();

    const int total = n * n;
    for (int t = tid; t < total; t += 256) {
        int a = t / n, b = t - a * n;
        if (b > a) {
            float4 A = mb[a], B = mb[b];
            // exact float32 op order of the reference:
            float iw = fminf(A.z, B.z) - fmaxf(A.x, B.x);
            iw = fmaxf(iw, 0.0f);
            float ih = fminf(A.w, B.w) - fmaxf(A.y, B.y);
            ih = fmaxf(ih, 0.0f);
            float inter = iw * ih;
            float uni = ma[a] + ma[b] - inter;
            float iou = __fdiv_rn(inter, uni);   // IEEE-rounded divide
            if (iou > 0.5f) {
                int ra = mlist[a], rb = mlist[b];
                unsigned int rlo = (ra < rb) ? (unsigned int)ra : (unsigned int)rb;
                unsigned int rhi = (ra < rb) ? (unsigned int)rb : (unsigned int)ra;
                int idx = atomicAdd(paircnt, 1);
                if (idx < PAIR_CAP) pairs[idx] = (rlo << 13) | rhi;
            }
        }
    }
}

// ---------------- K3: fixpoint + outputs (fused) ------------------------
// 32 blocks x 256. Each block redundantly runs the Jacobi fixpoint over
// the (identical) edge list -- deterministic unique fixpoint == greedy
// scan (edges strictly increase rank => DAG) -- then writes its own 256
// output rows from LDS.
__global__ __launch_bounds__(256) void k_scanout(const unsigned int* __restrict__ pairs,
                                                 const int* __restrict__ paircnt,
                                                 const int* __restrict__ Vcnt,
                                                 const float* __restrict__ box,
                                                 const float* __restrict__ conf,
                                                 const int* __restrict__ clsArr,
                                                 const int* __restrict__ rankArr,
                                                 float* __restrict__ out) {
    __shared__ unsigned long long keep[NW];
    __shared__ unsigned long long sn[NW];
    __shared__ unsigned int eLds[ELDS_CAP];     // 32 KB edge staging
    __shared__ int chg;
    const int tid = threadIdx.x;
    const int V = *Vcnt;
    int E = *paircnt; if (E > PAIR_CAP) E = PAIR_CAP;
    const bool inLds = (E <= ELDS_CAP);
    if (inLds)
        for (int eI = tid; eI < E; eI += 256) eLds[eI] = pairs[eI];

    const int fullw = V >> 6, remb = V & 63;
    unsigned long long vm = 0ULL;
    if (tid < NW) {
        vm = (tid < fullw) ? ~0ULL
           : (tid == fullw && remb) ? ((1ULL << remb) - 1ULL) : 0ULL;
        keep[tid] = vm;                       // K0 = valid
    }
    __syncthreads();

    for (int round = 0; round < 8192; ++round) {
        if (tid < NW) sn[tid] = 0ULL;
        if (tid == 0) chg = 0;
        __syncthreads();
        if (inLds) {
            for (int eI = tid; eI < E; eI += 256) {
                unsigned int p = eLds[eI];
                int r = p >> 13, c = p & 8191;
                if ((keep[r >> 6] >> (r & 63)) & 1ULL)
                    atomicOr(&sn[c >> 6], 1ULL << (c & 63));
            }
        } else {
            for (int eI = tid; eI < E; eI += 256) {
                unsigned int p = pairs[eI];
                int r = p >> 13, c = p & 8191;
                if ((keep[r >> 6] >> (r & 63)) & 1ULL)
                    atomicOr(&sn[c >> 6], 1ULL << (c & 63));
            }
        }
        __syncthreads();
        if (tid < NW) {
            unsigned long long nk = vm & ~sn[tid];
            if (nk != keep[tid]) { keep[tid] = nk; chg = 1; }
        }
        __syncthreads();
        if (!chg) break;                      // uniform (LDS, post-barrier)
    }

    // outputs for this block's 256 elements (keep read from own LDS)
    const int i = blockIdx.x * 256 + tid;
    const int r = rankArr[i];
    const float m = (float)((keep[r >> 6] >> (r & 63)) & 1ULL);
    float4 b = ((const float4*)box)[i];
    out[i * 5 + 0] = b.x * m;
    out[i * 5 + 1] = b.y * m;
    out[i * 5 + 2] = b.z * m;
    out[i * 5 + 3] = b.w * m;
    out[i * 5 + 4] = conf[i] * m;
    out[5 * N + i] = (float)clsArr[i];
    out[6 * N + i] = m;
}

// ---------------- launch -------------------------------------------------
extern "C" void kernel_launch(void* const* d_in, const int* in_sizes, int n_in,
                              void* d_out, int out_size, void* d_ws, size_t ws_size,
                              hipStream_t stream) {
    const float* box    = (const float*)d_in[0];
    const float* conf   = (const float*)d_in[1];
    const float* logits = (const float*)d_in[2];
    float* out = (float*)d_out;

    char* ws = (char*)d_ws;
    int*    rankArr = (int*)   (ws + 0);                 // 32 KB
    int*    clsArr  = (int*)   (ws + 32768);             // 32 KB
    int*    Vcnt    = (int*)   (ws + 65536);             // 4 B
    int*    paircnt = (int*)   (ws + 65600);             // 4 B
    float4* sbx     = (float4*)(ws + 131072);            // 128 KB
    float*  sarea   = (float*) (ws + 262144);            // 32 KB
    int*    scls    = (int*)   (ws + 294912);            // 32 KB
    unsigned int* pairs = (unsigned int*)(ws + 393216);  // 4 MB

    k_prepsort<<<N / NOWN, 256, 0, stream>>>(box, conf, logits, sbx, sarea,
                                             scls, rankArr, clsArr, Vcnt, paircnt);
    k_pairs2<<<NCLS, 256, 0, stream>>>(sbx, sarea, scls, Vcnt, pairs, paircnt);
    k_scanout<<<N / 256, 256, 0, stream>>>(pairs, paircnt, Vcnt, box, conf,
                                           clsArr, rankArr, out);
}

// Round 7
// 86.452 us; speedup vs baseline: 2.5164x; 1.1361x over previous
//
#include <hip/hip_runtime.h>
#include <stdint.h>

#define N 8192
#define NCLS 80
#define CCAP 128            // per-class member cap (expected ~51; 10.8 sigma)

// Within-class order key: ascending key == descending conf (conf>0.5 =>
// positive => bit-monotonic), tie -> lower index. Identical relative order
// to the reference's global stable argsort restricted to one class.
__device__ __forceinline__ unsigned long long makeKey(float c, int idx) {
    return ((unsigned long long)(~__float_as_uint(c)) << 32) | (unsigned int)idx;
}

// ---------------- K1: argmax + cls channel + invalid rows ---------------
// 512 blocks x 256 thr; 16 threads per element, float4-cooperative logits
// read (validated in round 6). Writes cls for ALL rows; writes complete
// zero rows for invalid elements (valid rows are written by k_nms, so
// every output byte is written every iteration).
__global__ __launch_bounds__(256) void k_cls(
    const float* __restrict__ conf,
    const float* __restrict__ logits,
    int* __restrict__ clsArr,
    float* __restrict__ out)
{
    const int tid = threadIdx.x;
    const int i = blockIdx.x * 16 + (tid >> 4);
    const int s = tid & 15;

    // thread s covers logits[4s..4s+3] (and [64+4s..67+4s] for s<4) in
    // ascending index order with strict > => first-max-wins within thread;
    // combine prefers greater value, tie -> lower index => exact argmax.
    const float4* lp4 = (const float4*)(logits + (size_t)i * NCLS);
    float4 v = lp4[s];
    int bi = 4 * s;
    float best = v.x;
    if (v.y > best) { best = v.y; bi = 4 * s + 1; }
    if (v.z > best) { best = v.z; bi = 4 * s + 2; }
    if (v.w > best) { best = v.w; bi = 4 * s + 3; }
    if (s < 4) {
        float4 w = lp4[16 + s];
        int b1 = 64 + 4 * s;
        if (w.x > best) { best = w.x; bi = b1; }
        if (w.y > best) { best = w.y; bi = b1 + 1; }
        if (w.z > best) { best = w.z; bi = b1 + 2; }
        if (w.w > best) { best = w.w; bi = b1 + 3; }
    }
    for (int off = 8; off; off >>= 1) {
        float ob = __shfl_down(best, off, 16);
        int   oi = __shfl_down(bi, off, 16);
        if (ob > best || (ob == best && oi < bi)) { best = ob; bi = oi; }
    }

    if (s == 0) {
        clsArr[i] = bi;
        out[5 * N + i] = (float)bi;
        if (!(conf[i] > 0.5f)) {         // invalid: full zero row here
            out[i * 5 + 0] = 0.0f;
            out[i * 5 + 1] = 0.0f;
            out[i * 5 + 2] = 0.0f;
            out[i * 5 + 3] = 0.0f;
            out[i * 5 + 4] = 0.0f;
            out[6 * N + i] = 0.0f;
        }
    }
}

// ---------------- K2: per-class exact NMS + valid-row outputs -----------
// One block per class. Cross-class pairs never suppress (same_cls gate),
// and the global stable sort preserves within-class relative order, so
// the reference's global greedy scan decomposes exactly into 80
// independent per-class greedy scans. Here: bucket members, rank in
// class, IoU suppression-bit matrix (exact fp32 op order + __fdiv_rn),
// then a bit-exact sequential greedy over <=128 bits by one thread.
__global__ __launch_bounds__(256) void k_nms(
    const float* __restrict__ box,
    const float* __restrict__ conf,
    const int* __restrict__ clsArr,
    float* __restrict__ out)
{
#pragma clang fp contract(off)
    __shared__ int n;
    __shared__ unsigned short uidx[CCAP];           // unsorted member idx
    __shared__ unsigned long long ukey[CCAP];
    __shared__ unsigned short sidx[CCAP];           // sorted by class rank
    __shared__ float4 sbox[CCAP];                   // corners x1,y1,x2,y2
    __shared__ float  sar[CCAP];
    __shared__ unsigned long long supmat[CCAP][2];  // bit b set: a suppresses b
    __shared__ unsigned long long keepm[2];

    const int tid = threadIdx.x;
    const int cls = blockIdx.x;

    if (tid == 0) n = 0;
    supmat[tid >> 1][tid & 1] = 0ULL;               // 256 words, 1/thread
    __syncthreads();

    // bucket this class's valid members
    for (int i = tid; i < N; i += 256) {
        float c = conf[i];
        if (c > 0.5f && clsArr[i] == cls) {
            int p = atomicAdd(&n, 1);
            if (p < CCAP) { uidx[p] = (unsigned short)i; ukey[p] = makeKey(c, i); }
        }
    }
    __syncthreads();
    int nn = n; if (nn > CCAP) nn = CCAP;

    // exact in-class rank (stable key) + scatter + stage geometry
    if (tid < nn) {
        unsigned long long mk = ukey[tid];
        int r = 0;
        for (int k = 0; k < nn; ++k) r += (ukey[k] < mk) ? 1 : 0;
        int i = uidx[tid];
        float4 b = ((const float4*)box)[i];          // x, y, w, h
        float hw = b.z * 0.5f, hh = b.w * 0.5f;      // == w/2 exactly
        sidx[r] = (unsigned short)i;
        sbox[r] = make_float4(b.x - hw, b.y - hh, b.x + hw, b.y + hh);
        sar[r]  = b.z * b.w;
    }
    __syncthreads();

    // pairwise IoU -> suppression bits (a = earlier rank, b = later)
    const int total = nn * nn;
    for (int t = tid; t < total; t += 256) {
        int a = t / nn, b = t - a * nn;
        if (b > a) {
            float4 A = sbox[a], B = sbox[b];
            // exact float32 op order of the reference:
            float iw = fminf(A.z, B.z) - fmaxf(A.x, B.x);
            iw = fmaxf(iw, 0.0f);
            float ih = fminf(A.w, B.w) - fmaxf(A.y, B.y);
            ih = fmaxf(ih, 0.0f);
            float inter = iw * ih;
            float uni = sar[a] + sar[b] - inter;
            float iou = __fdiv_rn(inter, uni);       // IEEE-rounded divide
            if (iou > 0.5f)
                atomicOr(&supmat[a][b >> 6], 1ULL << (b & 63));
        }
    }
    __syncthreads();

    // sequential greedy scan (reference semantics, bit-exact): a kept row
    // suppresses its marked later rows; supmat[a] holds only bits b>a.
    if (tid == 0) {
        unsigned long long k0 = (nn >= 64) ? ~0ULL : ((1ULL << nn) - 1ULL);
        unsigned long long k1 = (nn >= 128) ? ~0ULL
                              : (nn > 64) ? ((1ULL << (nn - 64)) - 1ULL) : 0ULL;
        for (int a = 0; a < nn; ++a) {
            bool ka = (a < 64) ? ((k0 >> a) & 1ULL) : ((k1 >> (a - 64)) & 1ULL);
            if (ka) { k0 &= ~supmat[a][0]; k1 &= ~supmat[a][1]; }
        }
        keepm[0] = k0; keepm[1] = k1;
    }
    __syncthreads();

    // output rows for this class's members (box/conf re-reads are L1-hot)
    if (tid < nn) {
        int i = sidx[tid];
        float m = (float)((keepm[tid >> 6] >> (tid & 63)) & 1ULL);
        float4 b = ((const float4*)box)[i];
        out[i * 5 + 0] = b.x * m;
        out[i * 5 + 1] = b.y * m;
        out[i * 5 + 2] = b.z * m;
        out[i * 5 + 3] = b.w * m;
        out[i * 5 + 4] = conf[i] * m;
        out[6 * N + i] = m;
    }
}

// ---------------- launch -------------------------------------------------
extern "C" void kernel_launch(void* const* d_in, const int* in_sizes, int n_in,
                              void* d_out, int out_size, void* d_ws, size_t ws_size,
                              hipStream_t stream) {
    const float* box    = (const float*)d_in[0];
    const float* conf   = (const float*)d_in[1];
    const float* logits = (const float*)d_in[2];
    float* out = (float*)d_out;

    int* clsArr = (int*)d_ws;                        // 32 KB

    k_cls<<<N / 16, 256, 0, stream>>>(conf, logits, clsArr, out);
    k_nms<<<NCLS, 256, 0, stream>>>(box, conf, clsArr, out);
}